// Round 5
// baseline (753.431 us; speedup 1.0000x reference)
//
#include <hip/hip_runtime.h>
#include <hip/hip_bf16.h>
#include <hip/hip_fp16.h>

#define NNODE 2048
#define NGRAPH 16

__device__ __forceinline__ int lmap(int m) { return m == 0 ? 0 : (m < 4 ? 1 : (m < 9 ? 2 : 3)); }

__device__ __forceinline__ float f4get(const float4& v, int j) {
    return j == 0 ? v.x : (j == 1 ? v.y : (j == 2 ? v.z : v.w));
}

// pack two floats as fp16 pair in a u32 (lo = a, hi = b)
__device__ __forceinline__ uint32_t f2h2(float a, float b) {
    __half2 h2 = __floats2half2_rn(a, b);
    return *reinterpret_cast<uint32_t*>(&h2);
}
__device__ __forceinline__ float2 h2f2(uint32_t u) {
    __half2 h2 = *reinterpret_cast<__half2*>(&u);
    return __half22float2(h2);
}

__device__ __forceinline__ void sph16(float x, float y, float z, float* Y) {
    Y[0] = 0.28209479177f;
    Y[1] = 0.4886025119f * y; Y[2] = 0.4886025119f * z; Y[3] = 0.4886025119f * x;
    Y[4] = 1.09254843059f * x * y;
    Y[5] = 1.09254843059f * y * z;
    Y[6] = 0.31539156525f * (3.f * z * z - 1.f);
    Y[7] = 1.09254843059f * x * z;
    Y[8] = 0.54627421529f * (x * x - y * y);
    Y[9]  = 0.59004358992f * y * (3.f * x * x - y * y);
    Y[10] = 2.89061144264f * x * y * z;
    Y[11] = 0.45704579946f * y * (5.f * z * z - 1.f);
    Y[12] = 0.37317633259f * z * (5.f * z * z - 3.f);
    Y[13] = 0.45704579946f * x * (5.f * z * z - 1.f);
    Y[14] = 1.44530572132f * z * (x * x - y * y);
    Y[15] = 0.59004358992f * x * (x * x - 3.f * y * y);
}

#define PROC_SRC(aa, u0, u1, u2, u3, h0v) { \
    int a_ = a0 + (aa); \
    float w_ = alphas[a_]; \
    const float* ysa = &yss[a_ * 17]; \
    float hb1 = (h0v) + 1.f; \
    float sc0 = S[aa][0] * hb1, sc1 = S[aa][1] * hb1; \
    float sc2 = S[aa][2] * hb1, sc3 = S[aa][3] * hb1; \
    acc[0]  = fmaf(w_, fmaf((u0).x, R[aa][0], sc0 * ysa[0]),  acc[0]); \
    acc[1]  = fmaf(w_, fmaf((u0).y, R[aa][1], sc1 * ysa[1]),  acc[1]); \
    acc[2]  = fmaf(w_, fmaf((u0).z, R[aa][1], sc1 * ysa[2]),  acc[2]); \
    acc[3]  = fmaf(w_, fmaf((u0).w, R[aa][1], sc1 * ysa[3]),  acc[3]); \
    acc[4]  = fmaf(w_, fmaf((u1).x, R[aa][2], sc2 * ysa[4]),  acc[4]); \
    acc[5]  = fmaf(w_, fmaf((u1).y, R[aa][2], sc2 * ysa[5]),  acc[5]); \
    acc[6]  = fmaf(w_, fmaf((u1).z, R[aa][2], sc2 * ysa[6]),  acc[6]); \
    acc[7]  = fmaf(w_, fmaf((u1).w, R[aa][2], sc2 * ysa[7]),  acc[7]); \
    acc[8]  = fmaf(w_, fmaf((u2).x, R[aa][2], sc2 * ysa[8]),  acc[8]); \
    acc[9]  = fmaf(w_, fmaf((u2).y, R[aa][3], sc3 * ysa[9]),  acc[9]); \
    acc[10] = fmaf(w_, fmaf((u2).z, R[aa][3], sc3 * ysa[10]), acc[10]); \
    acc[11] = fmaf(w_, fmaf((u2).w, R[aa][3], sc3 * ysa[11]), acc[11]); \
    acc[12] = fmaf(w_, fmaf((u3).x, R[aa][3], sc3 * ysa[12]), acc[12]); \
    acc[13] = fmaf(w_, fmaf((u3).y, R[aa][3], sc3 * ysa[13]), acc[13]); \
    acc[14] = fmaf(w_, fmaf((u3).z, R[aa][3], sc3 * ysa[14]), acc[14]); \
    acc[15] = fmaf(w_, fmaf((u3).w, R[aa][3], sc3 * ysa[15]), acc[15]); \
    }

// One fused layer. 3 blocks/CU (LDS ~49KB).
__global__ __launch_bounds__(256, 3) void k_layer(
    const float* __restrict__ x, const float* __restrict__ h,
    const float* __restrict__ vpre, const float* __restrict__ wqk,
    const float* __restrict__ w1, const float* __restrict__ b1,
    const float* __restrict__ rW, const float* __restrict__ sW,
    const float* __restrict__ Wskip, const float* __restrict__ Wo,
    const float* __restrict__ gw, const float* __restrict__ gb,
    const float* __restrict__ Wv_n, const float* __restrict__ Wq_n, const float* __restrict__ Wk_n,
    const float* __restrict__ WvO, const float* __restrict__ WqO, const float* __restrict__ WkO,
    float* __restrict__ hnew, float* __restrict__ vpre_n, float* __restrict__ wqk_n,
    float* __restrict__ wq2, float* __restrict__ U,
    int layer, int last)
{
    // pass-2 layout: rwswP[d*128 + ((l*8+jq)^(d&7))*4 + jj] = fp16 pair (rW,sW) for j = jq*4+jj
    __shared__ __align__(16) uint32_t rwswP[4096];
    __shared__ __align__(16) float rhs[128 * 36]; // rh; later P[8][528]; later wsk / WvO-lo
    __shared__ __align__(16) float yss[128 * 17]; // Ys; later hs[512]
    __shared__ __align__(16) float ub[1056];      // phase A: xs[384]|w1s[512]; post: hnS[528]|aggL[528]
    __shared__ float b1s[32];
    __shared__ float wqks[32];
    __shared__ float alphas[128];
    __shared__ float red[256];
    __shared__ float scale[128];
    __shared__ float sh_inv;

    int n = blockIdx.x, t = threadIdx.x;
    int g = n >> 7, b = n & 127;
    int gbase = g << 7;

    float* xs = ub;           // [384]
    float* w1s = ub + 384;    // [512]

    for (int o = t; o < 384; o += 256) xs[o] = x[gbase * 3 + o];
    for (int o = t; o < 512; o += 256) w1s[o] = w1[layer * 512 + o];
    if (t < 32) { b1s[t] = b1[layer * 32 + t]; wqks[t] = wqk[n * 32 + t]; }
    for (int idx = t; idx < 4096; idx += 256) {
        int l = idx >> 10, j = (idx >> 5) & 31, d2 = idx & 31;
        int o = d2 * 128 + ((((l << 3) + (j >> 2)) ^ (d2 & 7)) << 2) + (j & 3);
        int src = layer * 4096 + l * 1024 + j * 32 + d2;
        rwswP[o] = f2h2(rW[src], sW[src]);
    }
    __syncthreads();

    // ---- phase A: geometry, rh, partial logit (all 256 threads; 2 d-halves) ----
    {
        int a = t & 127, dh = t >> 7;
        float rx = xs[b * 3 + 0] - xs[a * 3 + 0];
        float ry = xs[b * 3 + 1] - xs[a * 3 + 1];
        float rz = xs[b * 3 + 2] - xs[a * 3 + 2];
        float dd = sqrtf(rx * rx + ry * ry + rz * rz + 1e-12f);
        float inv = 1.f / dd;
        float ys[16];
        sph16(rx * inv, ry * inv, rz * inv, ys);
        if (dh == 0) {
#pragma unroll
            for (int m = 0; m < 16; m++) yss[a * 17 + m] = ys[m];
        }
        float rbf[16];
#pragma unroll
        for (int j = 0; j < 16; j++) {
            float dc = dd - (4.f / 15.f) * j;
            rbf[j] = __expf(-2.f * dc * dc);
        }
        float lpart = 0.f;
        int d0 = dh * 16;
        for (int d2 = 0; d2 < 16; d2++) {
            int d = d0 + d2;
            float s = b1s[d];
#pragma unroll
            for (int j = 0; j < 16; j++) s = fmaf(rbf[j], w1s[j * 32 + d], s);
            s = fmaxf(s, 0.f);
            rhs[a * 36 + d] = s;
            lpart = fmaf(s, wqks[d], lpart);
        }
        red[t] = lpart;
    }
    __syncthreads();
    if (t < 128) alphas[t] = (red[t] + red[t + 128]) * 0.17677669529663687f; // 1/sqrt(32)
    __syncthreads();

    // ---- segment softmax over 127 valid edges (wave-level shuffle reductions) ----
    if (t < 128) {
        float m = (t != b) ? alphas[t] : -1e30f;
#pragma unroll
        for (int off = 32; off > 0; off >>= 1) m = fmaxf(m, __shfl_xor(m, off));
        if ((t & 63) == 0) red[t >> 6] = m;
    }
    __syncthreads();
    {
        float mx = fmaxf(red[0], red[1]);
        if (t < 128) {
            float e = (t != b) ? __expf(alphas[t] - mx) : 0.f;
            alphas[t] = e;
            float s = e;
#pragma unroll
            for (int off = 32; off > 0; off >>= 1) s += __shfl_xor(s, off);
            if ((t & 63) == 0) red[2 + (t >> 6)] = s;
        }
    }
    __syncthreads();
    if (t == 0) sh_inv = 1.f / (red[2] + red[3]);

    // ---- pass 2: register-blocked R/S GEMM + weighted aggregate ----
    int grp = t >> 5, d = t & 31;
    int dbase = d * 128, dx = d & 7;
    float acc[16];
#pragma unroll
    for (int m = 0; m < 16; m++) acc[m] = 0.f;

    for (int chunk = 0; chunk < 2; chunk++) {
        int a0 = grp * 16 + chunk * 8;
        float R[8][4], S[8][4];
#pragma unroll
        for (int aa = 0; aa < 8; aa++)
#pragma unroll
            for (int l = 0; l < 4; l++) { R[aa][l] = 0.f; S[aa][l] = 0.f; }

#pragma unroll 2
        for (int jq = 0; jq < 8; jq++) {
            float4 rh4[8];
#pragma unroll
            for (int aa = 0; aa < 8; aa++)
                rh4[aa] = *reinterpret_cast<const float4*>(&rhs[(a0 + aa) * 36 + jq * 4]);
#pragma unroll
            for (int l = 0; l < 4; l++) {
                uint4 wp = *reinterpret_cast<const uint4*>(
                    &rwswP[dbase + ((((l << 3) + jq) ^ dx) << 2)]);
#pragma unroll
                for (int jj = 0; jj < 4; jj++) {
                    uint32_t w = jj == 0 ? wp.x : (jj == 1 ? wp.y : (jj == 2 ? wp.z : wp.w));
                    float2 w2 = h2f2(w);
#pragma unroll
                    for (int aa = 0; aa < 8; aa++) {
                        float rv = f4get(rh4[aa], jj);
                        R[aa][l] = fmaf(rv, w2.x, R[aa][l]);
                        S[aa][l] = fmaf(rv, w2.y, S[aa][l]);
                    }
                }
            }
        }

        // epilogue: 2-deep double-buffered global loads
        float4 A0, A1, A2, A3, B0, B1, B2, B3; float Ah, Bh;
        {
            int nb = (gbase + a0) * 512 + d * 16;
            const float4* p4 = reinterpret_cast<const float4*>(vpre + nb);
            A0 = p4[0]; A1 = p4[1]; A2 = p4[2]; A3 = p4[3]; Ah = h[nb];
            int nb2 = (gbase + a0 + 1) * 512 + d * 16;
            const float4* q4 = reinterpret_cast<const float4*>(vpre + nb2);
            B0 = q4[0]; B1 = q4[1]; B2 = q4[2]; B3 = q4[3]; Bh = h[nb2];
        }
#pragma unroll
        for (int ap = 0; ap < 4; ap++) {
            int aa = ap * 2;
            {
                float4 u0 = A0, u1 = A1, u2 = A2, u3 = A3; float h0v = Ah;
                if (ap < 3) {
                    int nb2 = (gbase + a0 + aa + 2) * 512 + d * 16;
                    const float4* p4 = reinterpret_cast<const float4*>(vpre + nb2);
                    A0 = p4[0]; A1 = p4[1]; A2 = p4[2]; A3 = p4[3]; Ah = h[nb2];
                }
                PROC_SRC(aa, u0, u1, u2, u3, h0v)
            }
            {
                float4 u0 = B0, u1 = B1, u2 = B2, u3 = B3; float h0v = Bh;
                if (ap < 3) {
                    int nb2 = (gbase + a0 + aa + 3) * 512 + d * 16;
                    const float4* p4 = reinterpret_cast<const float4*>(vpre + nb2);
                    B0 = p4[0]; B1 = p4[1]; B2 = p4[2]; B3 = p4[3]; Bh = h[nb2];
                }
                PROC_SRC(aa + 1, u0, u1, u2, u3, h0v)
            }
        }
    }
    __syncthreads();   // all pass-2 LDS reads (rhs/rwswP/yss) done

    // S1: partials into P (overlay rhs); stage h[n] (overlay yss); stage Wo (float bits in rwswP)
    float* P = rhs;
#pragma unroll
    for (int m = 0; m < 16; m++) P[grp * 528 + m * 33 + d] = acc[m];
    float* hs = yss;
    for (int o = t; o < 512; o += 256) hs[o] = h[n * 512 + o];
    for (int o = t; o < 4096; o += 256) rwswP[o] = __float_as_uint(Wo[layer * 4096 + o]);
    __syncthreads();

    // S2: reduce partials -> aggL[m*33+c]
    float* hnS = ub;          // [528]
    float* aggL = ub + 528;   // [528]
    float invs = sh_inv;
    for (int o = t; o < 512; o += 256) {
        int m = o >> 5, c = o & 31;
        float s = 0.f;
#pragma unroll
        for (int gg = 0; gg < 8; gg++) s += P[gg * 528 + m * 33 + c];
        aggL[m * 33 + c] = s * invs;
    }
    __syncthreads();

    // S3: stage Wskip into rhs (fp32), P dead
    for (int o = t; o < 4096; o += 256) rhs[o] = Wskip[layer * 4096 + o];
    __syncthreads();

    // S4: post GEMM: hn = h@Wskip + agg@Wo
    for (int o = t; o < 512; o += 256) {
        int m = o >> 5, dd = o & 31, l = lmap(m);
        float s = 0.f;
        const float* wa = &rhs[l * 1024 + dd];
        const uint32_t* wb = &rwswP[l * 1024 + dd];
        const float* hrow = &hs[m];
        const float* arow = &aggL[m * 33];
#pragma unroll
        for (int c = 0; c < 32; c++) {
            s = fmaf(hrow[c * 16], wa[c * 32], s);
            s = fmaf(arow[c], __uint_as_float(wb[c * 32]), s);
        }
        hnS[m * 33 + dd] = s;
    }
    __syncthreads();

    // S5: norm gate compute + stage next-stage value weights
    if (t < 128) {
        int dd = t >> 2, l = t & 3;
        int m0 = l * l, cnt = 2 * l + 1;
        float s = 1e-12f;
        for (int m = m0; m < m0 + cnt; m++) { float v = hnS[m * 33 + dd]; s = fmaf(v, v, s); }
        float nr = sqrtf(s);
        float phi = fmaxf(nr * gw[(layer * 4 + l) * 32 + dd] + gb[(layer * 4 + l) * 32 + dd], 0.f);
        scale[dd * 4 + l] = phi / (nr + 1e-6f);
    }
    if (!last) {
        for (int o = t; o < 4096; o += 256) rwswP[o] = __float_as_uint(Wv_n[o]);
    } else {
        for (int o = t; o < 4096; o += 256) {
            rhs[o] = WvO[o];                                   // l = 0,1
            rwswP[o] = __float_as_uint(WvO[4096 + o]);         // l = 2,3
        }
    }
    __syncthreads();

    // S6: apply gate, write hnew
    for (int o = t; o < 512; o += 256) {
        int dd = o >> 4, m = o & 15;
        float v = hnS[m * 33 + dd] * scale[dd * 4 + lmap(m)];
        hnew[n * 512 + o] = v;
        hnS[m * 33 + dd] = v;
    }
    __syncthreads();

    if (!last) {
        for (int o = t; o < 512; o += 256) {
            int dd = o >> 4, m = o & 15, l = lmap(m);
            float s = 0.f;
            const uint32_t* wv = &rwswP[l * 1024 + dd];
            const float* hrow = &hnS[m * 33];
#pragma unroll
            for (int c = 0; c < 32; c++) s = fmaf(hrow[c], __uint_as_float(wv[c * 32]), s);
            vpre_n[n * 512 + o] = s;
        }
        if (t < 32) {
            float s = 0.f;
#pragma unroll
            for (int c = 0; c < 32; c++) s = fmaf(hnS[c * 33], Wq_n[c * 32 + t], s);
            red[t] = s;
        }
        __syncthreads();
        if (t < 32) {
            float s = 0.f;
#pragma unroll
            for (int j = 0; j < 32; j++) s = fmaf(Wk_n[t * 32 + j], red[j], s);
            wqk_n[n * 32 + t] = s;
        }
    } else {
        for (int o = t; o < 1024; o += 256) {
            int j = o >> 4, m = o & 15, l = lmap(m);
            float s = 0.f;
            const float* hrow = &hnS[m * 33];
            if (l < 2) {
                const float* wv = &rhs[l * 2048 + j];
#pragma unroll
                for (int c = 0; c < 32; c++) s = fmaf(hrow[c], wv[c * 64], s);
            } else {
                const uint32_t* wv = &rwswP[(l - 2) * 2048 + j];
#pragma unroll
                for (int c = 0; c < 32; c++) s = fmaf(hrow[c], __uint_as_float(wv[c * 64]), s);
            }
            U[n * 1024 + o] = s;
        }
        if (t < 64) {
            float s = 0.f;
#pragma unroll
            for (int c = 0; c < 32; c++) s = fmaf(hnS[c * 33], WqO[c * 64 + t], s);
            red[t] = s;
        }
        __syncthreads();
        if (t < 32) {
            float s = 0.f;
#pragma unroll
            for (int j = 0; j < 64; j++) s = fmaf(WkO[t * 64 + j], red[j], s);
            wq2[n * 32 + t] = s;
        }
    }
}

// Output-stage edge kernel + fused out_post (hout). 3 blocks/CU.
__global__ __launch_bounds__(256, 3) void k_out_edge(
    const float* __restrict__ x, const float* __restrict__ h,
    const float* __restrict__ w1o, const float* __restrict__ b1o,
    const float* __restrict__ wq2, const float* __restrict__ roW,
    const float* __restrict__ U, const float* __restrict__ WoO,
    const float* __restrict__ WskipO, float* __restrict__ hout)
{
    __shared__ uint32_t rosP[4096];               // fp16 pairs of roW c-neighbors
    __shared__ __align__(16) float rhs[128 * 36];
    __shared__ __align__(16) float yss[128 * 17];
    __shared__ float xs[384];
    __shared__ float w1s[512];
    __shared__ float b1s[32];
    __shared__ float wq2s[32];
    __shared__ float alphas[128];
    __shared__ float red[256];
    __shared__ float agg64s[64];
    __shared__ float sh_inv;

    int n = blockIdx.x, t = threadIdx.x;
    int g = n >> 7, b = n & 127;
    int gbase = g << 7;

    for (int o = t; o < 384; o += 256) xs[o] = x[gbase * 3 + o];
    for (int o = t; o < 512; o += 256) w1s[o] = w1o[o];
    if (t < 32) { b1s[t] = b1o[t]; wq2s[t] = wq2[n * 32 + t]; }
    for (int o = t; o < 4096; o += 256) {
        int j = o & 63, lc = o >> 6, cp = lc & 15, l = lc >> 4;
        rosP[o] = f2h2(roW[(l * 32 + 2 * cp) * 64 + j], roW[(l * 32 + 2 * cp + 1) * 64 + j]);
    }
    __syncthreads();

    // phase A split across 256 threads
    {
        int a = t & 127, dh = t >> 7;
        float rx = xs[b * 3 + 0] - xs[a * 3 + 0];
        float ry = xs[b * 3 + 1] - xs[a * 3 + 1];
        float rz = xs[b * 3 + 2] - xs[a * 3 + 2];
        float dd = sqrtf(rx * rx + ry * ry + rz * rz + 1e-12f);
        float inv = 1.f / dd;
        float ys[16];
        sph16(rx * inv, ry * inv, rz * inv, ys);
        if (dh == 0) {
#pragma unroll
            for (int m = 0; m < 16; m++) yss[a * 17 + m] = ys[m];
        }
        float rbf[16];
#pragma unroll
        for (int j = 0; j < 16; j++) {
            float dc = dd - (4.f / 15.f) * j;
            rbf[j] = __expf(-2.f * dc * dc);
        }
        float lpart = 0.f;
        int d0 = dh * 16;
        for (int d2 = 0; d2 < 16; d2++) {
            int d = d0 + d2;
            float s = b1s[d];
#pragma unroll
            for (int j = 0; j < 16; j++) s = fmaf(rbf[j], w1s[j * 32 + d], s);
            s = fmaxf(s, 0.f);
            rhs[a * 36 + d] = s;
            lpart = fmaf(s, wq2s[d], lpart);
        }
        red[t] = lpart;
    }
    __syncthreads();
    if (t < 128) alphas[t] = (red[t] + red[t + 128]) * 0.125f; // 1/sqrt(64)
    __syncthreads();

    if (t < 128) {
        float m = (t != b) ? alphas[t] : -1e30f;
#pragma unroll
        for (int off = 32; off > 0; off >>= 1) m = fmaxf(m, __shfl_xor(m, off));
        if ((t & 63) == 0) red[t >> 6] = m;
    }
    __syncthreads();
    {
        float mx = fmaxf(red[0], red[1]);
        if (t < 128) {
            float e = (t != b) ? __expf(alphas[t] - mx) : 0.f;
            alphas[t] = e;
            float s = e;
#pragma unroll
            for (int off = 32; off > 0; off >>= 1) s += __shfl_xor(s, off);
            if ((t & 63) == 0) red[2 + (t >> 6)] = s;
        }
    }
    __syncthreads();
    if (t == 0) sh_inv = 1.f / (red[2] + red[3]);
    __syncthreads();

    int grp = t >> 6, j = t & 63;
    float accO = 0.f;
    for (int chunk = 0; chunk < 4; chunk++) {
        int a0 = grp * 32 + chunk * 8;
        float RO[8][4];
#pragma unroll
        for (int aa = 0; aa < 8; aa++)
#pragma unroll
            for (int l = 0; l < 4; l++) RO[aa][l] = 0.f;

#pragma unroll 2
        for (int cq = 0; cq < 8; cq++) {
            float4 rh4[8];
#pragma unroll
            for (int aa = 0; aa < 8; aa++)
                rh4[aa] = *reinterpret_cast<const float4*>(&rhs[(a0 + aa) * 36 + cq * 4]);
#pragma unroll
            for (int l = 0; l < 4; l++) {
#pragma unroll
                for (int ch = 0; ch < 2; ch++) {
                    float2 w2 = h2f2(rosP[(l * 16 + cq * 2 + ch) * 64 + j]);
#pragma unroll
                    for (int aa = 0; aa < 8; aa++) {
                        RO[aa][l] = fmaf(f4get(rh4[aa], 2 * ch), w2.x, RO[aa][l]);
                        RO[aa][l] = fmaf(f4get(rh4[aa], 2 * ch + 1), w2.y, RO[aa][l]);
                    }
                }
            }
        }

        float4 A0, A1, A2, A3, B0, B1, B2, B3;
        {
            const float4* p4 = reinterpret_cast<const float4*>(U + (gbase + a0) * 1024 + j * 16);
            A0 = p4[0]; A1 = p4[1]; A2 = p4[2]; A3 = p4[3];
            const float4* q4 = reinterpret_cast<const float4*>(U + (gbase + a0 + 1) * 1024 + j * 16);
            B0 = q4[0]; B1 = q4[1]; B2 = q4[2]; B3 = q4[3];
        }
#define PROC_O(aa, u0, u1, u2, u3) { \
        int a_ = a0 + (aa); \
        float w_ = alphas[a_]; \
        if (w_ != 0.f) { \
            const float* ysa = &yss[a_ * 17]; \
            float cv0 = ysa[0] * (u0).x; \
            float cv1 = fmaf(ysa[1], (u0).y, fmaf(ysa[2], (u0).z, ysa[3] * (u0).w)); \
            float cv2 = fmaf(ysa[4], (u1).x, fmaf(ysa[5], (u1).y, fmaf(ysa[6], (u1).z, fmaf(ysa[7], (u1).w, ysa[8] * (u2).x)))); \
            float cv3 = fmaf(ysa[9], (u2).y, fmaf(ysa[10], (u2).z, fmaf(ysa[11], (u2).w, \
                        fmaf(ysa[12], (u3).x, fmaf(ysa[13], (u3).y, fmaf(ysa[14], (u3).z, ysa[15] * (u3).w)))))); \
            float s_ = fmaf(cv0, RO[aa][0], fmaf(cv1, RO[aa][1], fmaf(cv2, RO[aa][2], cv3 * RO[aa][3]))); \
            accO = fmaf(w_, s_, accO); \
        } }
#pragma unroll
        for (int ap = 0; ap < 4; ap++) {
            int aa = ap * 2;
            {
                float4 u0 = A0, u1 = A1, u2 = A2, u3 = A3;
                if (ap < 3) {
                    const float4* p4 = reinterpret_cast<const float4*>(U + (gbase + a0 + aa + 2) * 1024 + j * 16);
                    A0 = p4[0]; A1 = p4[1]; A2 = p4[2]; A3 = p4[3];
                }
                PROC_O(aa, u0, u1, u2, u3)
            }
            {
                float4 u0 = B0, u1 = B1, u2 = B2, u3 = B3;
                if (ap < 3) {
                    const float4* p4 = reinterpret_cast<const float4*>(U + (gbase + a0 + aa + 3) * 1024 + j * 16);
                    B0 = p4[0]; B1 = p4[1]; B2 = p4[2]; B3 = p4[3];
                }
                PROC_O(aa + 1, u0, u1, u2, u3)
            }
        }
#undef PROC_O
    }
    red[t] = accO;
    __syncthreads();
    if (t < 64) agg64s[t] = (red[t] + red[64 + t] + red[128 + t] + red[192 + t]) * sh_inv;
    __syncthreads();

    if (t < 64) {
        float s = 0.f;
#pragma unroll
        for (int c = 0; c < 64; c++) s = fmaf(agg64s[c], WoO[c * 64 + t], s);
        const float* hr = &h[n * 512];
#pragma unroll
        for (int c = 0; c < 32; c++) s = fmaf(hr[c * 16], WskipO[c * 64 + t], s);
        hout[n * 64 + t] = s;
    }
}

__global__ __launch_bounds__(64) void k_final(
    const float* __restrict__ hout, const float* __restrict__ Whid,
    const float* __restrict__ bhid, const float* __restrict__ Wout,
    const float* __restrict__ bout, float* __restrict__ out)
{
    __shared__ float pooled[64], hid[64];
    int g = blockIdx.x, t = threadIdx.x;
    float s = 0.f;
    for (int p = 0; p < 128; p++) s += hout[(g * 128 + p) * 64 + t];
    pooled[t] = s * (1.f / 128.f);
    __syncthreads();
    float hv = bhid[t];
#pragma unroll
    for (int c = 0; c < 64; c++) hv = fmaf(pooled[c], Whid[c * 64 + t], hv);
    hid[t] = fmaxf(hv, 0.f);
    __syncthreads();
    if (t < 15) {
        float o = bout[t];
#pragma unroll
        for (int c = 0; c < 64; c++) o = fmaf(hid[c], Wout[c * 15 + t], o);
        out[g * 15 + t] = o;
    }
}

extern "C" void kernel_launch(void* const* d_in, const int* in_sizes, int n_in,
                              void* d_out, int out_size, void* d_ws, size_t ws_size,
                              hipStream_t stream) {
    const float* x      = (const float*)d_in[0];
    const float* w1     = (const float*)d_in[1];
    const float* b1     = (const float*)d_in[2];
    const float* rW     = (const float*)d_in[3];
    const float* sW     = (const float*)d_in[4];
    const float* Wv     = (const float*)d_in[5];
    const float* Wq     = (const float*)d_in[6];
    const float* Wk     = (const float*)d_in[7];
    const float* Wo     = (const float*)d_in[8];
    const float* Wskip  = (const float*)d_in[9];
    const float* gw     = (const float*)d_in[10];
    const float* gb     = (const float*)d_in[11];
    const float* w1o    = (const float*)d_in[12];
    const float* b1o    = (const float*)d_in[13];
    const float* roW    = (const float*)d_in[14];
    const float* WvO    = (const float*)d_in[15];
    const float* WqO    = (const float*)d_in[16];
    const float* WkO    = (const float*)d_in[17];
    const float* WoO    = (const float*)d_in[18];
    const float* WskipO = (const float*)d_in[19];
    const float* Whid   = (const float*)d_in[20];
    const float* bhid   = (const float*)d_in[21];
    const float* Wout   = (const float*)d_in[22];
    const float* bout   = (const float*)d_in[23];
    float* out = (float*)d_out;

    float* ws = (float*)d_ws;
    float* h0    = ws;
    float* h1    = h0 + NNODE * 512;
    float* vA    = h1 + NNODE * 512;
    float* wqkA  = vA + NNODE * 512;
    float* vB    = wqkA + NNODE * 32;
    float* wqkB  = vB + NNODE * 512;
    float* wq2   = wqkB + NNODE * 32;
    float* U     = wq2 + NNODE * 32;
    float* hout  = U + NNODE * 1024;

    hipMemsetAsync(h0, 0, NNODE * 512 * sizeof(float), stream);
    hipMemsetAsync(vA, 0, (NNODE * 512 + NNODE * 32) * sizeof(float), stream);

    for (int i = 0; i < 4; i++) {
        const float* hc  = (i & 1) ? h1 : h0;
        float*       hn  = (i & 1) ? h0 : h1;
        const float* vin  = (i & 1) ? vB : vA;
        const float* qin  = (i & 1) ? wqkB : wqkA;
        float*       vout = (i & 1) ? vA : vB;
        float*       qout = (i & 1) ? wqkA : wqkB;
        int last = (i == 3);
        k_layer<<<NNODE, 256, 0, stream>>>(
            x, hc, vin, qin, w1, b1, rW, sW, Wskip, Wo, gw, gb,
            Wv + (last ? 0 : (i + 1) * 4096),
            Wq + (last ? 0 : (i + 1) * 1024),
            Wk + (last ? 0 : (i + 1) * 1024),
            WvO, WqO, WkO,
            hn, vout, qout, wq2, U, i, last);
    }
    k_out_edge<<<NNODE, 256, 0, stream>>>(x, h0, w1o, b1o, wq2, roW, U, WoO, WskipO, hout);
    k_final<<<NGRAPH, 64, 0, stream>>>(hout, Whid, bhid, Wout, bout, out);
}

// Round 6
// 750.549 us; speedup vs baseline: 1.0038x; 1.0038x over previous
//
#include <hip/hip_runtime.h>
#include <hip/hip_bf16.h>
#include <hip/hip_fp16.h>

#define NNODE 2048
#define NGRAPH 16

using f16x8 = __attribute__((ext_vector_type(8))) _Float16;
using f32x4 = __attribute__((ext_vector_type(4))) float;

__device__ __forceinline__ int lmap(int m) { return m == 0 ? 0 : (m < 4 ? 1 : (m < 9 ? 2 : 3)); }

__device__ __forceinline__ float f4get(const float4& v, int j) {
    return j == 0 ? v.x : (j == 1 ? v.y : (j == 2 ? v.z : v.w));
}

// pack two floats as fp16 pair in a u32 (lo = a, hi = b)
__device__ __forceinline__ uint32_t f2h2(float a, float b) {
    __half2 h2 = __floats2half2_rn(a, b);
    return *reinterpret_cast<uint32_t*>(&h2);
}
__device__ __forceinline__ float2 h2f2(uint32_t u) {
    __half2 h2 = *reinterpret_cast<__half2*>(&u);
    return __half22float2(h2);
}

__device__ __forceinline__ void sph16(float x, float y, float z, float* Y) {
    Y[0] = 0.28209479177f;
    Y[1] = 0.4886025119f * y; Y[2] = 0.4886025119f * z; Y[3] = 0.4886025119f * x;
    Y[4] = 1.09254843059f * x * y;
    Y[5] = 1.09254843059f * y * z;
    Y[6] = 0.31539156525f * (3.f * z * z - 1.f);
    Y[7] = 1.09254843059f * x * z;
    Y[8] = 0.54627421529f * (x * x - y * y);
    Y[9]  = 0.59004358992f * y * (3.f * x * x - y * y);
    Y[10] = 2.89061144264f * x * y * z;
    Y[11] = 0.45704579946f * y * (5.f * z * z - 1.f);
    Y[12] = 0.37317633259f * z * (5.f * z * z - 3.f);
    Y[13] = 0.45704579946f * x * (5.f * z * z - 1.f);
    Y[14] = 1.44530572132f * z * (x * x - y * y);
    Y[15] = 0.59004358992f * x * (x * x - 3.f * y * y);
}

// MFMA phase for one dh-half: fills D[2][8]; q = rs*4 + l, nt = rs*8 + l*2 + DH
#define MFMA_HALF(DH) \
    _Pragma("unroll") \
    for (int q = 0; q < 8; q++) { \
        int nt_ = ((q >> 2) << 3) + ((q & 3) << 1) + (DH); \
        f16x8 Bf = *reinterpret_cast<const f16x8*>(wBH + nt_ * 512 + lane * 8); \
        _Pragma("unroll") \
        for (int mt = 0; mt < 2; mt++) { \
            f32x4 z = {0.f, 0.f, 0.f, 0.f}; \
            z = __builtin_amdgcn_mfma_f32_16x16x32_f16(Ahi[mt], Bf, z, 0, 0, 0); \
            z = __builtin_amdgcn_mfma_f32_16x16x32_f16(Alo[mt], Bf, z, 0, 0, 0); \
            D[mt][q] = z; \
        } \
    }

// Epilogue for one dh-half into ACC[16]
#define EPIHALF(DH, ACC) { \
    const int d_ = (DH) * 16 + n; \
    _Pragma("unroll") \
    for (int mt = 0; mt < 2; mt++) { \
        _Pragma("unroll") \
        for (int reg = 0; reg < 4; reg++) { \
            int a_ = (w * 2 + mt) * 16 + kb * 4 + reg; \
            float w_ = alphas[a_]; \
            const float* ysa = &yss[a_ * 17]; \
            int nb = (gbase + a_) * 512 + d_ * 16; \
            const float4* p4 = reinterpret_cast<const float4*>(vpre + nb); \
            float4 u0 = p4[0], u1 = p4[1], u2 = p4[2], u3 = p4[3]; \
            float hb1 = h[nb] + 1.f; \
            float R0 = D[mt][0][reg], R1 = D[mt][1][reg]; \
            float R2 = D[mt][2][reg], R3 = D[mt][3][reg]; \
            float Sc0 = D[mt][4][reg] * hb1, Sc1 = D[mt][5][reg] * hb1; \
            float Sc2 = D[mt][6][reg] * hb1, Sc3 = D[mt][7][reg] * hb1; \
            ACC[0]  = fmaf(w_, fmaf(u0.x, R0, Sc0 * ysa[0]),  ACC[0]); \
            ACC[1]  = fmaf(w_, fmaf(u0.y, R1, Sc1 * ysa[1]),  ACC[1]); \
            ACC[2]  = fmaf(w_, fmaf(u0.z, R1, Sc1 * ysa[2]),  ACC[2]); \
            ACC[3]  = fmaf(w_, fmaf(u0.w, R1, Sc1 * ysa[3]),  ACC[3]); \
            ACC[4]  = fmaf(w_, fmaf(u1.x, R2, Sc2 * ysa[4]),  ACC[4]); \
            ACC[5]  = fmaf(w_, fmaf(u1.y, R2, Sc2 * ysa[5]),  ACC[5]); \
            ACC[6]  = fmaf(w_, fmaf(u1.z, R2, Sc2 * ysa[6]),  ACC[6]); \
            ACC[7]  = fmaf(w_, fmaf(u1.w, R2, Sc2 * ysa[7]),  ACC[7]); \
            ACC[8]  = fmaf(w_, fmaf(u2.x, R2, Sc2 * ysa[8]),  ACC[8]); \
            ACC[9]  = fmaf(w_, fmaf(u2.y, R3, Sc3 * ysa[9]),  ACC[9]); \
            ACC[10] = fmaf(w_, fmaf(u2.z, R3, Sc3 * ysa[10]), ACC[10]); \
            ACC[11] = fmaf(w_, fmaf(u2.w, R3, Sc3 * ysa[11]), ACC[11]); \
            ACC[12] = fmaf(w_, fmaf(u3.x, R3, Sc3 * ysa[12]), ACC[12]); \
            ACC[13] = fmaf(w_, fmaf(u3.y, R3, Sc3 * ysa[13]), ACC[13]); \
            ACC[14] = fmaf(w_, fmaf(u3.z, R3, Sc3 * ysa[14]), ACC[14]); \
            ACC[15] = fmaf(w_, fmaf(u3.w, R3, Sc3 * ysa[15]), ACC[15]); \
        } \
    } }

// One fused layer. 3 blocks/CU (LDS ~51KB).
__global__ __launch_bounds__(256, 3) void k_layer(
    const float* __restrict__ x, const float* __restrict__ h,
    const float* __restrict__ vpre, const float* __restrict__ wqk,
    const float* __restrict__ w1, const float* __restrict__ b1,
    const float* __restrict__ rW, const float* __restrict__ sW,
    const float* __restrict__ Wskip, const float* __restrict__ Wo,
    const float* __restrict__ gw, const float* __restrict__ gb,
    const float* __restrict__ Wv_n, const float* __restrict__ Wq_n, const float* __restrict__ Wk_n,
    const float* __restrict__ WvO, const float* __restrict__ WqO, const float* __restrict__ WkO,
    float* __restrict__ hnew, float* __restrict__ vpre_n, float* __restrict__ wqk_n,
    float* __restrict__ wq2, float* __restrict__ U,
    int layer, int last)
{
    // bufA: rh fp16-hi [2560 u32 = 128 rows x 40 shorts] + rh fp16-lo [2560 u32];
    //       later P[4][2][16][16] f32 (8KB); later Wskip f32 (16KB) / WvO-lo (16KB)
    __shared__ __align__(16) uint32_t bufA[5120];
    // wB: B fragments fp16 [nt=16][lane=64][8] (16KB); later Wo / Wv_n / WvO-hi (f32 bits)
    __shared__ __align__(16) uint32_t wB[4096];
    __shared__ __align__(16) float yss[128 * 17]; // Ys; later hs[512]
    __shared__ __align__(16) float ub[1056];      // phase A: xs[384]|w1s[512]; post: hnS[528]|aggL[528]
    __shared__ float b1s[32];
    __shared__ float wqks[32];
    __shared__ float alphas[128];
    __shared__ float red[256];
    __shared__ float scale[128];
    __shared__ float sh_inv;

    int nblk = blockIdx.x, t = threadIdx.x;
    int g = nblk >> 7, b = nblk & 127;
    int gbase = g << 7;

    float* xs = ub;           // [384]
    float* w1s = ub + 384;    // [512]

    for (int o = t; o < 384; o += 256) xs[o] = x[gbase * 3 + o];
    for (int o = t; o < 512; o += 256) w1s[o] = w1[layer * 512 + o];
    if (t < 32) { b1s[t] = b1[layer * 32 + t]; wqks[t] = wqk[nblk * 32 + t]; }
    // stage rW|sW as fp16 B-fragments: nt = rs*8 + l*2 + dh, lane = kb*16 + (d&15), pair along j
    for (int idx = t; idx < 4096; idx += 256) {
        int d2 = idx & 31, j2 = (idx >> 5) & 15, l = (idx >> 9) & 3, rs = idx >> 11;
        const float* W = rs ? sW : rW;
        int srcb = layer * 4096 + l * 1024 + (2 * j2) * 32 + d2;
        float v0 = W[srcb], v1 = W[srcb + 32];
        int nt = rs * 8 + l * 2 + (d2 >> 4);
        int lid = ((j2 >> 2) << 4) + (d2 & 15);
        wB[nt * 256 + lid * 4 + (j2 & 3)] = f2h2(v0, v1);
    }
    __syncthreads();

    // ---- phase A: geometry, rh (stored as fp16 hi+lo), partial logit ----
    {
        int a = t & 127, dh = t >> 7;
        float rx = xs[b * 3 + 0] - xs[a * 3 + 0];
        float ry = xs[b * 3 + 1] - xs[a * 3 + 1];
        float rz = xs[b * 3 + 2] - xs[a * 3 + 2];
        float dd = sqrtf(rx * rx + ry * ry + rz * rz + 1e-12f);
        float inv = 1.f / dd;
        float ys[16];
        sph16(rx * inv, ry * inv, rz * inv, ys);
        if (dh == 0) {
#pragma unroll
            for (int m = 0; m < 16; m++) yss[a * 17 + m] = ys[m];
        }
        float rbf[16];
#pragma unroll
        for (int j = 0; j < 16; j++) {
            float dc = dd - (4.f / 15.f) * j;
            rbf[j] = __expf(-2.f * dc * dc);
        }
        float lpart = 0.f;
        int d0 = dh * 16;
        float sprev = 0.f;
        for (int d2 = 0; d2 < 16; d2++) {
            int d = d0 + d2;
            float s = b1s[d];
#pragma unroll
            for (int j = 0; j < 16; j++) s = fmaf(rbf[j], w1s[j * 32 + d], s);
            s = fmaxf(s, 0.f);
            lpart = fmaf(s, wqks[d], lpart);
            if (d2 & 1) {
                __half h0 = __float2half_rn(sprev), h1 = __float2half_rn(s);
                float l0f = sprev - __half2float(h0), l1f = s - __half2float(h1);
                uint32_t hp = (uint32_t)__half_as_ushort(h0) |
                              ((uint32_t)__half_as_ushort(h1) << 16);
                uint32_t lp = (uint32_t)__half_as_ushort(__float2half_rn(l0f)) |
                              ((uint32_t)__half_as_ushort(__float2half_rn(l1f)) << 16);
                int wi = a * 20 + dh * 8 + (d2 >> 1);
                bufA[wi] = hp;
                bufA[2560 + wi] = lp;
            }
            sprev = s;
        }
        red[t] = lpart;
    }
    __syncthreads();
    if (t < 128) alphas[t] = (red[t] + red[t + 128]) * 0.17677669529663687f; // 1/sqrt(32)
    __syncthreads();

    // ---- segment softmax over 127 valid edges (wave shuffle reductions) ----
    if (t < 128) {
        float m = (t != b) ? alphas[t] : -1e30f;
#pragma unroll
        for (int off = 32; off > 0; off >>= 1) m = fmaxf(m, __shfl_xor(m, off));
        if ((t & 63) == 0) red[t >> 6] = m;
    }
    __syncthreads();
    {
        float mx = fmaxf(red[0], red[1]);
        if (t < 128) {
            float e = (t != b) ? __expf(alphas[t] - mx) : 0.f;
            alphas[t] = e;
            float s = e;
#pragma unroll
            for (int off = 32; off > 0; off >>= 1) s += __shfl_xor(s, off);
            if ((t & 63) == 0) red[2 + (t >> 6)] = s;
        }
    }
    __syncthreads();
    if (t == 0) sh_inv = 1.f / (red[2] + red[3]);

    // ---- pass 2: MFMA R/S GEMM + weighted aggregate ----
    int lane = t & 63, w = t >> 6;
    int n = lane & 15, kb = lane >> 4;

    const _Float16* rhHiH = reinterpret_cast<const _Float16*>(bufA);
    const _Float16* rhLoH = reinterpret_cast<const _Float16*>(bufA + 2560);
    const _Float16* wBH   = reinterpret_cast<const _Float16*>(wB);

    f16x8 Ahi[2], Alo[2];
#pragma unroll
    for (int mt = 0; mt < 2; mt++) {
        int row = (w * 2 + mt) * 16 + n;
        Ahi[mt] = *reinterpret_cast<const f16x8*>(rhHiH + row * 40 + kb * 8);
        Alo[mt] = *reinterpret_cast<const f16x8*>(rhLoH + row * 40 + kb * 8);
    }

    float acc0[16], acc1[16];
#pragma unroll
    for (int m = 0; m < 16; m++) { acc0[m] = 0.f; acc1[m] = 0.f; }

    {   // dh = 0
        f32x4 D[2][8];
        MFMA_HALF(0)
        EPIHALF(0, acc0)
    }
    {   // dh = 1
        f32x4 D[2][8];
        MFMA_HALF(1)
        EPIHALF(1, acc1)
    }

    // cross-kb butterfly reduce (sources within wave)
#pragma unroll
    for (int m = 0; m < 16; m++) {
        float v0 = acc0[m];
        v0 += __shfl_xor(v0, 16); v0 += __shfl_xor(v0, 32);
        acc0[m] = v0;
        float v1 = acc1[m];
        v1 += __shfl_xor(v1, 16); v1 += __shfl_xor(v1, 32);
        acc1[m] = v1;
    }
    __syncthreads();   // all pass-2 LDS reads (bufA/wB/yss) done

    // S1: partials into P (overlay bufA); stage h[n] (overlay yss); stage Wo into wB
    float* P = reinterpret_cast<float*>(bufA);
    if (lane < 16) {
#pragma unroll
        for (int m = 0; m < 16; m++) {
            P[w * 512 + m * 16 + n] = acc0[m];
            P[w * 512 + 256 + m * 16 + n] = acc1[m];
        }
    }
    float* hs = yss;
    for (int o = t; o < 512; o += 256) hs[o] = h[nblk * 512 + o];
    for (int o = t; o < 4096; o += 256) wB[o] = __float_as_uint(Wo[layer * 4096 + o]);
    __syncthreads();

    // S2: reduce partials -> aggL[m*33+c]  (c = dh*16 + n)
    float* hnS = ub;          // [528]
    float* aggL = ub + 528;   // [528]
    float invs = sh_inv;
    for (int o = t; o < 512; o += 256) {
        int m = o >> 5, c = o & 31;
        int dh = c >> 4, nn = c & 15;
        float s = 0.f;
#pragma unroll
        for (int ww = 0; ww < 4; ww++) s += P[ww * 512 + dh * 256 + m * 16 + nn];
        aggL[m * 33 + c] = s * invs;
    }
    __syncthreads();

    // S3: stage Wskip into bufA (fp32), P dead
    float* bufF = reinterpret_cast<float*>(bufA);
    for (int o = t; o < 4096; o += 256) bufF[o] = Wskip[layer * 4096 + o];
    __syncthreads();

    // S4: post GEMM: hn = h@Wskip + agg@Wo
    for (int o = t; o < 512; o += 256) {
        int m = o >> 5, dd = o & 31, l = lmap(m);
        float s = 0.f;
        const float* wa = &bufF[l * 1024 + dd];
        const uint32_t* wb = &wB[l * 1024 + dd];
        const float* hrow = &hs[m];
        const float* arow = &aggL[m * 33];
#pragma unroll
        for (int c = 0; c < 32; c++) {
            s = fmaf(hrow[c * 16], wa[c * 32], s);
            s = fmaf(arow[c], __uint_as_float(wb[c * 32]), s);
        }
        hnS[m * 33 + dd] = s;
    }
    __syncthreads();

    // S5: norm gate compute + stage next-stage value weights
    if (t < 128) {
        int dd = t >> 2, l = t & 3;
        int m0 = l * l, cnt = 2 * l + 1;
        float s = 1e-12f;
        for (int m = m0; m < m0 + cnt; m++) { float v = hnS[m * 33 + dd]; s = fmaf(v, v, s); }
        float nr = sqrtf(s);
        float phi = fmaxf(nr * gw[(layer * 4 + l) * 32 + dd] + gb[(layer * 4 + l) * 32 + dd], 0.f);
        scale[dd * 4 + l] = phi / (nr + 1e-6f);
    }
    if (!last) {
        for (int o = t; o < 4096; o += 256) wB[o] = __float_as_uint(Wv_n[o]);
    } else {
        for (int o = t; o < 4096; o += 256) {
            bufF[o] = WvO[o];                               // l = 0,1
            wB[o] = __float_as_uint(WvO[4096 + o]);         // l = 2,3
        }
    }
    __syncthreads();

    // S6: apply gate, write hnew
    for (int o = t; o < 512; o += 256) {
        int dd = o >> 4, m = o & 15;
        float v = hnS[m * 33 + dd] * scale[dd * 4 + lmap(m)];
        hnew[nblk * 512 + o] = v;
        hnS[m * 33 + dd] = v;
    }
    __syncthreads();

    if (!last) {
        for (int o = t; o < 512; o += 256) {
            int dd = o >> 4, m = o & 15, l = lmap(m);
            float s = 0.f;
            const uint32_t* wv = &wB[l * 1024 + dd];
            const float* hrow = &hnS[m * 33];
#pragma unroll
            for (int c = 0; c < 32; c++) s = fmaf(hrow[c], __uint_as_float(wv[c * 32]), s);
            vpre_n[nblk * 512 + o] = s;
        }
        if (t < 32) {
            float s = 0.f;
#pragma unroll
            for (int c = 0; c < 32; c++) s = fmaf(hnS[c * 33], Wq_n[c * 32 + t], s);
            red[t] = s;
        }
        __syncthreads();
        if (t < 32) {
            float s = 0.f;
#pragma unroll
            for (int j = 0; j < 32; j++) s = fmaf(Wk_n[t * 32 + j], red[j], s);
            wqk_n[nblk * 32 + t] = s;
        }
    } else {
        for (int o = t; o < 1024; o += 256) {
            int j = o >> 4, m = o & 15, l = lmap(m);
            float s = 0.f;
            const float* hrow = &hnS[m * 33];
            if (l < 2) {
                const float* wv = &bufF[l * 2048 + j];
#pragma unroll
                for (int c = 0; c < 32; c++) s = fmaf(hrow[c], wv[c * 64], s);
            } else {
                const uint32_t* wv = &wB[(l - 2) * 2048 + j];
#pragma unroll
                for (int c = 0; c < 32; c++) s = fmaf(hrow[c], __uint_as_float(wv[c * 64]), s);
            }
            U[nblk * 1024 + o] = s;
        }
        if (t < 64) {
            float s = 0.f;
#pragma unroll
            for (int c = 0; c < 32; c++) s = fmaf(hnS[c * 33], WqO[c * 64 + t], s);
            red[t] = s;
        }
        __syncthreads();
        if (t < 32) {
            float s = 0.f;
#pragma unroll
            for (int j = 0; j < 64; j++) s = fmaf(WkO[t * 64 + j], red[j], s);
            wq2[nblk * 32 + t] = s;
        }
    }
}

// Output-stage edge kernel + fused out_post (hout). 3 blocks/CU.
__global__ __launch_bounds__(256, 3) void k_out_edge(
    const float* __restrict__ x, const float* __restrict__ h,
    const float* __restrict__ w1o, const float* __restrict__ b1o,
    const float* __restrict__ wq2, const float* __restrict__ roW,
    const float* __restrict__ U, const float* __restrict__ WoO,
    const float* __restrict__ WskipO, float* __restrict__ hout)
{
    __shared__ uint32_t rosP[4096];               // fp16 pairs of roW c-neighbors
    __shared__ __align__(16) float rhs[128 * 36];
    __shared__ __align__(16) float yss[128 * 17];
    __shared__ float xs[384];
    __shared__ float w1s[512];
    __shared__ float b1s[32];
    __shared__ float wq2s[32];
    __shared__ float alphas[128];
    __shared__ float red[256];
    __shared__ float agg64s[64];
    __shared__ float sh_inv;

    int n = blockIdx.x, t = threadIdx.x;
    int g = n >> 7, b = n & 127;
    int gbase = g << 7;

    for (int o = t; o < 384; o += 256) xs[o] = x[gbase * 3 + o];
    for (int o = t; o < 512; o += 256) w1s[o] = w1o[o];
    if (t < 32) { b1s[t] = b1o[t]; wq2s[t] = wq2[n * 32 + t]; }
    for (int o = t; o < 4096; o += 256) {
        int j = o & 63, lc = o >> 6, cp = lc & 15, l = lc >> 4;
        rosP[o] = f2h2(roW[(l * 32 + 2 * cp) * 64 + j], roW[(l * 32 + 2 * cp + 1) * 64 + j]);
    }
    __syncthreads();

    // phase A split across 256 threads
    {
        int a = t & 127, dh = t >> 7;
        float rx = xs[b * 3 + 0] - xs[a * 3 + 0];
        float ry = xs[b * 3 + 1] - xs[a * 3 + 1];
        float rz = xs[b * 3 + 2] - xs[a * 3 + 2];
        float dd = sqrtf(rx * rx + ry * ry + rz * rz + 1e-12f);
        float inv = 1.f / dd;
        float ys[16];
        sph16(rx * inv, ry * inv, rz * inv, ys);
        if (dh == 0) {
#pragma unroll
            for (int m = 0; m < 16; m++) yss[a * 17 + m] = ys[m];
        }
        float rbf[16];
#pragma unroll
        for (int j = 0; j < 16; j++) {
            float dc = dd - (4.f / 15.f) * j;
            rbf[j] = __expf(-2.f * dc * dc);
        }
        float lpart = 0.f;
        int d0 = dh * 16;
        for (int d2 = 0; d2 < 16; d2++) {
            int d = d0 + d2;
            float s = b1s[d];
#pragma unroll
            for (int j = 0; j < 16; j++) s = fmaf(rbf[j], w1s[j * 32 + d], s);
            s = fmaxf(s, 0.f);
            rhs[a * 36 + d] = s;
            lpart = fmaf(s, wq2s[d], lpart);
        }
        red[t] = lpart;
    }
    __syncthreads();
    if (t < 128) alphas[t] = (red[t] + red[t + 128]) * 0.125f; // 1/sqrt(64)
    __syncthreads();

    if (t < 128) {
        float m = (t != b) ? alphas[t] : -1e30f;
#pragma unroll
        for (int off = 32; off > 0; off >>= 1) m = fmaxf(m, __shfl_xor(m, off));
        if ((t & 63) == 0) red[t >> 6] = m;
    }
    __syncthreads();
    {
        float mx = fmaxf(red[0], red[1]);
        if (t < 128) {
            float e = (t != b) ? __expf(alphas[t] - mx) : 0.f;
            alphas[t] = e;
            float s = e;
#pragma unroll
            for (int off = 32; off > 0; off >>= 1) s += __shfl_xor(s, off);
            if ((t & 63) == 0) red[2 + (t >> 6)] = s;
        }
    }
    __syncthreads();
    if (t == 0) sh_inv = 1.f / (red[2] + red[3]);
    __syncthreads();

    int grp = t >> 6, j = t & 63;
    float accO = 0.f;
    for (int chunk = 0; chunk < 4; chunk++) {
        int a0 = grp * 32 + chunk * 8;
        float RO[8][4];
#pragma unroll
        for (int aa = 0; aa < 8; aa++)
#pragma unroll
            for (int l = 0; l < 4; l++) RO[aa][l] = 0.f;

#pragma unroll 2
        for (int cq = 0; cq < 8; cq++) {
            float4 rh4[8];
#pragma unroll
            for (int aa = 0; aa < 8; aa++)
                rh4[aa] = *reinterpret_cast<const float4*>(&rhs[(a0 + aa) * 36 + cq * 4]);
#pragma unroll
            for (int l = 0; l < 4; l++) {
#pragma unroll
                for (int ch = 0; ch < 2; ch++) {
                    float2 w2 = h2f2(rosP[(l * 16 + cq * 2 + ch) * 64 + j]);
#pragma unroll
                    for (int aa = 0; aa < 8; aa++) {
                        RO[aa][l] = fmaf(f4get(rh4[aa], 2 * ch), w2.x, RO[aa][l]);
                        RO[aa][l] = fmaf(f4get(rh4[aa], 2 * ch + 1), w2.y, RO[aa][l]);
                    }
                }
            }
        }

        float4 A0, A1, A2, A3, B0, B1, B2, B3;
        {
            const float4* p4 = reinterpret_cast<const float4*>(U + (gbase + a0) * 1024 + j * 16);
            A0 = p4[0]; A1 = p4[1]; A2 = p4[2]; A3 = p4[3];
            const float4* q4 = reinterpret_cast<const float4*>(U + (gbase + a0 + 1) * 1024 + j * 16);
            B0 = q4[0]; B1 = q4[1]; B2 = q4[2]; B3 = q4[3];
        }
#define PROC_O(aa, u0, u1, u2, u3) { \
        int a_ = a0 + (aa); \
        float w_ = alphas[a_]; \
        if (w_ != 0.f) { \
            const float* ysa = &yss[a_ * 17]; \
            float cv0 = ysa[0] * (u0).x; \
            float cv1 = fmaf(ysa[1], (u0).y, fmaf(ysa[2], (u0).z, ysa[3] * (u0).w)); \
            float cv2 = fmaf(ysa[4], (u1).x, fmaf(ysa[5], (u1).y, fmaf(ysa[6], (u1).z, fmaf(ysa[7], (u1).w, ysa[8] * (u2).x)))); \
            float cv3 = fmaf(ysa[9], (u2).y, fmaf(ysa[10], (u2).z, fmaf(ysa[11], (u2).w, \
                        fmaf(ysa[12], (u3).x, fmaf(ysa[13], (u3).y, fmaf(ysa[14], (u3).z, ysa[15] * (u3).w)))))); \
            float s_ = fmaf(cv0, RO[aa][0], fmaf(cv1, RO[aa][1], fmaf(cv2, RO[aa][2], cv3 * RO[aa][3]))); \
            accO = fmaf(w_, s_, accO); \
        } }
#pragma unroll
        for (int ap = 0; ap < 4; ap++) {
            int aa = ap * 2;
            {
                float4 u0 = A0, u1 = A1, u2 = A2, u3 = A3;
                if (ap < 3) {
                    const float4* p4 = reinterpret_cast<const float4*>(U + (gbase + a0 + aa + 2) * 1024 + j * 16);
                    A0 = p4[0]; A1 = p4[1]; A2 = p4[2]; A3 = p4[3];
                }
                PROC_O(aa, u0, u1, u2, u3)
            }
            {
                float4 u0 = B0, u1 = B1, u2 = B2, u3 = B3;
                if (ap < 3) {
                    const float4* p4 = reinterpret_cast<const float4*>(U + (gbase + a0 + aa + 3) * 1024 + j * 16);
                    B0 = p4[0]; B1 = p4[1]; B2 = p4[2]; B3 = p4[3];
                }
                PROC_O(aa + 1, u0, u1, u2, u3)
            }
        }
#undef PROC_O
    }
    red[t] = accO;
    __syncthreads();
    if (t < 64) agg64s[t] = (red[t] + red[64 + t] + red[128 + t] + red[192 + t]) * sh_inv;
    __syncthreads();

    if (t < 64) {
        float s = 0.f;
#pragma unroll
        for (int c = 0; c < 64; c++) s = fmaf(agg64s[c], WoO[c * 64 + t], s);
        const float* hr = &h[n * 512];
#pragma unroll
        for (int c = 0; c < 32; c++) s = fmaf(hr[c * 16], WskipO[c * 64 + t], s);
        hout[n * 64 + t] = s;
    }
}

__global__ __launch_bounds__(64) void k_final(
    const float* __restrict__ hout, const float* __restrict__ Whid,
    const float* __restrict__ bhid, const float* __restrict__ Wout,
    const float* __restrict__ bout, float* __restrict__ out)
{
    __shared__ float pooled[64], hid[64];
    int g = blockIdx.x, t = threadIdx.x;
    float s = 0.f;
    for (int p = 0; p < 128; p++) s += hout[(g * 128 + p) * 64 + t];
    pooled[t] = s * (1.f / 128.f);
    __syncthreads();
    float hv = bhid[t];
#pragma unroll
    for (int c = 0; c < 64; c++) hv = fmaf(pooled[c], Whid[c * 64 + t], hv);
    hid[t] = fmaxf(hv, 0.f);
    __syncthreads();
    if (t < 15) {
        float o = bout[t];
#pragma unroll
        for (int c = 0; c < 64; c++) o = fmaf(hid[c], Wout[c * 15 + t], o);
        out[g * 15 + t] = o;
    }
}

extern "C" void kernel_launch(void* const* d_in, const int* in_sizes, int n_in,
                              void* d_out, int out_size, void* d_ws, size_t ws_size,
                              hipStream_t stream) {
    const float* x      = (const float*)d_in[0];
    const float* w1     = (const float*)d_in[1];
    const float* b1     = (const float*)d_in[2];
    const float* rW     = (const float*)d_in[3];
    const float* sW     = (const float*)d_in[4];
    const float* Wv     = (const float*)d_in[5];
    const float* Wq     = (const float*)d_in[6];
    const float* Wk     = (const float*)d_in[7];
    const float* Wo     = (const float*)d_in[8];
    const float* Wskip  = (const float*)d_in[9];
    const float* gw     = (const float*)d_in[10];
    const float* gb     = (const float*)d_in[11];
    const float* w1o    = (const float*)d_in[12];
    const float* b1o    = (const float*)d_in[13];
    const float* roW    = (const float*)d_in[14];
    const float* WvO    = (const float*)d_in[15];
    const float* WqO    = (const float*)d_in[16];
    const float* WkO    = (const float*)d_in[17];
    const float* WoO    = (const float*)d_in[18];
    const float* WskipO = (const float*)d_in[19];
    const float* Whid   = (const float*)d_in[20];
    const float* bhid   = (const float*)d_in[21];
    const float* Wout   = (const float*)d_in[22];
    const float* bout   = (const float*)d_in[23];
    float* out = (float*)d_out;

    float* ws = (float*)d_ws;
    float* h0    = ws;
    float* h1    = h0 + NNODE * 512;
    float* vA    = h1 + NNODE * 512;
    float* wqkA  = vA + NNODE * 512;
    float* vB    = wqkA + NNODE * 32;
    float* wqkB  = vB + NNODE * 512;
    float* wq2   = wqkB + NNODE * 32;
    float* U     = wq2 + NNODE * 32;
    float* hout  = U + NNODE * 1024;

    hipMemsetAsync(h0, 0, NNODE * 512 * sizeof(float), stream);
    hipMemsetAsync(vA, 0, (NNODE * 512 + NNODE * 32) * sizeof(float), stream);

    for (int i = 0; i < 4; i++) {
        const float* hc  = (i & 1) ? h1 : h0;
        float*       hn  = (i & 1) ? h0 : h1;
        const float* vin  = (i & 1) ? vB : vA;
        const float* qin  = (i & 1) ? wqkB : wqkA;
        float*       vout = (i & 1) ? vA : vB;
        float*       qout = (i & 1) ? wqkA : wqkB;
        int last = (i == 3);
        k_layer<<<NNODE, 256, 0, stream>>>(
            x, hc, vin, qin, w1, b1, rW, sW, Wskip, Wo, gw, gb,
            Wv + (last ? 0 : (i + 1) * 4096),
            Wq + (last ? 0 : (i + 1) * 1024),
            Wk + (last ? 0 : (i + 1) * 1024),
            WvO, WqO, WkO,
            hn, vout, qout, wq2, U, i, last);
    }
    k_out_edge<<<NNODE, 256, 0, stream>>>(x, h0, w1o, b1o, wq2, roW, U, WoO, WskipO, hout);
    k_final<<<NGRAPH, 64, 0, stream>>>(hout, Whid, bhid, Wout, bout, out);
}